// Round 8
// baseline (145.366 us; speedup 1.0000x reference)
//
#include <hip/hip_runtime.h>
#include <math.h>

// JointAttentionMemoryBank via fp16 MFMA.  out = W @ softmax(W^T x / sqrt(D))
//   B=16 N=4096 D=128 M=1536.  fp32 in/out.
// R14 = R13 scaffolding (NT=64, 4 waves, SESS_M=128, skew p2(q)||p1mfma(q+1),
// 2 barriers/session, xs/Pbuf 136-stride LDS) with 32x32x16 fragments:
//   - LDS reads per wave-session halve (p1 bx 16->8, p2 P 16->8): LDS pipe
//     (R13's tallest, ~64% busy) drops ~2x. W-frag loads double (L1/L2 path,
//     W is L2-resident).
//   - Wave (wm2=w>>1, wn2=w&1): p1 owns m32 tiles {q*4+2wm2, +1} x n32=wn2;
//     p2 owns d32 {2wm2, 2wm2+1} x n32=wn2. acc[2]+c[2] f32x16 = 64 AGPR
//     (same budget as R13's 64); arch VGPR ~64 -> 4 waves/SIMD.
//   - All layouts from verified rounds: 32x32 C-map/P-write/epilogue (R8/R10
//     passed), km-major wd prep (R11 passed), xs/Pbuf/barrier (R6/R13).
// Ledger: bank-conflict counter structural (R12); exp2f slow, __expf fast;
// VGPR+AGPR <= 128/wave; skew legal but neutral (R13) - kept for chain count.

#define Bdim 16
#define Ndim 4096
#define Ddim 128
#define Mdim 1536
#define NT 64               // rows (n) per block
#define NTHREADS 256        // 4 waves
#define NSESS 12            // m-sessions (128 m each)
#define XPAD 136            // xs row stride f16
#define PPAD 136            // Pbuf row stride f16

typedef __attribute__((ext_vector_type(8)))  _Float16 f16x8;   // 4 VGPRs
typedef __attribute__((ext_vector_type(4)))  _Float16 f16x4;   // 8 B
typedef __attribute__((ext_vector_type(16))) float    f32x16;  // 32x32 MFMA C/D

// ---- prep: W (D,M) fp32 -> fragment-ordered fp16 (32x32x16 form) ----
// wt (phase-1 A = W^T, pre-scaled 1/sqrt(D)):
//   frag f = (mt32*8 + ks)*64 + l ; m = mt32*32 + (l&31), d = ks*16 + (l>>5)*8 + j
// wd (phase-2 A = W), km-major:
//   frag f = (km*4 + dt)*64 + l ; d = dt*32 + (l&31), m = km*16 + (l>>5)*8 + j
// One block per mt32 (48 blocks): coalesced 32m x 128d tile -> LDS, emit both.
// (R11-verified structure; scale swapped to plain 1/sqrt(D) for __expf.)
__global__ __launch_bounds__(256)
void jamb_prep(const float* __restrict__ w,
               _Float16* __restrict__ wt,
               _Float16* __restrict__ wd) {
    __shared__ float ts[32 * 132];        // [m][d], +4 pad
    const int t  = threadIdx.x;
    const int mt = blockIdx.x;            // 0..47
    #pragma unroll
    for (int i = 0; i < 16; ++i) {        // 4096 floats, coalesced rows
        const int f = t + i * 256;
        const int d = f >> 5;
        const int m = f & 31;
        ts[m * 132 + d] = w[(size_t)d * Mdim + mt * 32 + m];
    }
    __syncthreads();
    const float SC = 0.08838834764831843f;   // 1/sqrt(128)
    #pragma unroll
    for (int h = 0; h < 2; ++h) {         // wt: 2 frags/thread
        const int fr = t + h * 256;       // 0..511
        const int l  = fr & 63;
        const int ks = fr >> 6;           // 0..7
        const int m  = l & 31;
        const int d0 = ks * 16 + (l >> 5) * 8;
        f16x8 pk;
        #pragma unroll
        for (int j = 0; j < 8; ++j)
            pk[j] = (_Float16)(ts[m * 132 + d0 + j] * SC);
        *(f16x8*)&wt[(size_t)((mt * 8 + ks) * 64 + l) * 8] = pk;
    }
    #pragma unroll
    for (int h = 0; h < 2; ++h) {         // wd: 2 frags/thread (km = 2mt+h)
        const int l    = t & 63;
        const int dt   = t >> 6;          // 0..3
        const int km   = mt * 2 + h;
        const int d    = dt * 32 + (l & 31);
        const int mloc = h * 16 + (l >> 5) * 8;
        f16x8 pk;
        #pragma unroll
        for (int j = 0; j < 8; ++j)
            pk[j] = (_Float16)ts[(mloc + j) * 132 + d];
        *(f16x8*)&wd[(size_t)((km * 4 + dt) * 64 + l) * 8] = pk;
    }
}

__global__ __launch_bounds__(NTHREADS, 4)
void jamb_mfma_kernel(const float* __restrict__ x,
                      const _Float16* __restrict__ wt,
                      const _Float16* __restrict__ wd,
                      float* __restrict__ out) {
    __shared__ __align__(16) _Float16 xs[NT * XPAD];    // 17408 B
    __shared__ __align__(16) _Float16 Pbuf[NT * PPAD];  // 17408 B
    __shared__ float redsum[2][2][32];                  // 512 B  (total 35328 B)

    const int t   = threadIdx.x;
    const int w   = t >> 6;         // wave 0..3
    const int l   = t & 63;
    const int l31 = l & 31;
    const int hi  = l >> 5;
    const int wm2 = w >> 1;         // m-group (p1 m-tiles, p2 d-tiles)
    const int wn2 = w & 1;          // n32 owner

    const int blk   = blockIdx.x;
    const int b     = blk >> 6;             // 64 blocks per batch
    const int nbase = (blk & 63) * NT;

    // ---- stage x tile -> LDS fp16 (coalesced float4 reads; R6 verbatim) ----
    {
        const float* xb = x + (size_t)(b * Ndim + nbase) * Ddim;
        #pragma unroll
        for (int i = 0; i < 8; ++i) {
            const int f   = t + i * 256;        // float4 index, [0,2048)
            const int row = f >> 5;             // 32 float4 per row
            const int c4  = (f & 31) * 4;
            const float4 v = *(const float4*)(xb + row * Ddim + c4);
            f16x4 pk;
            pk[0] = (_Float16)v.x; pk[1] = (_Float16)v.y;
            pk[2] = (_Float16)v.z; pk[3] = (_Float16)v.w;
            *(f16x4*)&xs[row * XPAD + c4] = pk;
        }
    }
    __syncthreads();

    const f16x8* WT = (const f16x8*)wt;
    const f16x8* WD = (const f16x8*)wd;

    const int nrow = wn2 * 32 + l31;    // this lane's n row (xs/Pbuf/out)

    float ssum = 0.f;                   // unnormalized softmax sum for n=nrow
    f32x16 c[2];                        // p2 acc: d32 tiles {2wm2, 2wm2+1}
    c[0] = (f32x16)(0.f);
    c[1] = (f32x16)(0.f);
    f32x16 acc[2];                      // p1 S acc (skewed: holds session q+1)

    // ---- p1 MFMA for session q: S tiles (mt32 = q*4 + 2wm2 + i) x n32=wn2 ----
    auto p1mfma = [&](int q) {
        const int mtb = q * 4 + 2 * wm2;
        acc[0] = (f32x16)(0.f);
        acc[1] = (f32x16)(0.f);
        #pragma unroll
        for (int ks = 0; ks < 8; ++ks) {
            const f16x8 fh0 = WT[(size_t)((mtb + 0) * 8 + ks) * 64 + l];
            const f16x8 fh1 = WT[(size_t)((mtb + 1) * 8 + ks) * 64 + l];
            const f16x8 bx  = *(const f16x8*)&xs[nrow * XPAD + ks * 16 + hi * 8];
            acc[0] = __builtin_amdgcn_mfma_f32_32x32x16_f16(fh0, bx, acc[0], 0, 0, 0);
            acc[1] = __builtin_amdgcn_mfma_f32_32x32x16_f16(fh1, bx, acc[1], 0, 0, 0);
        }
    };

    // ---- exp + P write (session-local m cols; C-map m = (r&3)+8g+4hi) ----
    auto expwrite = [&]() {
        #pragma unroll
        for (int i = 0; i < 2; ++i) {
            const int mbase = (2 * wm2 + i) * 32;
            #pragma unroll
            for (int g = 0; g < 4; ++g) {
                const float e0 = __expf(acc[i][4 * g + 0]);
                const float e1 = __expf(acc[i][4 * g + 1]);
                const float e2 = __expf(acc[i][4 * g + 2]);
                const float e3 = __expf(acc[i][4 * g + 3]);
                ssum += (e0 + e1) + (e2 + e3);
                f16x4 pk;
                pk[0] = (_Float16)e0; pk[1] = (_Float16)e1;
                pk[2] = (_Float16)e2; pk[3] = (_Float16)e3;
                *(f16x4*)&Pbuf[nrow * PPAD + mbase + g * 8 + hi * 4] = pk;
            }
        }
    };

    // ---- p2 for session q: 8 ksteps of 16 m; wave owns d32 {2wm2,2wm2+1} ----
    auto p2 = [&](int q) {
        #pragma unroll
        for (int sk = 0; sk < 8; ++sk) {
            const int km = q * 8 + sk;
            const f16x8 a0 = WD[(size_t)(km * 4 + 2 * wm2 + 0) * 64 + l];
            const f16x8 a1 = WD[(size_t)(km * 4 + 2 * wm2 + 1) * 64 + l];
            const f16x8 pf = *(const f16x8*)&Pbuf[nrow * PPAD + sk * 16 + hi * 8];
            c[0] = __builtin_amdgcn_mfma_f32_32x32x16_f16(a0, pf, c[0], 0, 0, 0);
            c[1] = __builtin_amdgcn_mfma_f32_32x32x16_f16(a1, pf, c[1], 0, 0, 0);
        }
    };

    // ---- skewed pipeline (R13 pattern): p2(q) || p1mfma(q+1) ----
    p1mfma(0);
    expwrite();
    #pragma unroll 1
    for (int q = 0; q < NSESS; ++q) {
        __syncthreads();               // A: P(q) published
        p2(q);
        if (q + 1 < NSESS) p1mfma(q + 1);
        __syncthreads();               // B: Pbuf reads retired
        if (q + 1 < NSESS) expwrite();
    }

    // ---- softmax sums: fold hi halves (same n), cross-wm2 via LDS ----
    ssum += __shfl_xor(ssum, 32, 64);
    if (hi == 0) redsum[wn2][wm2][l31] = ssum;
    __syncthreads();
    const float inv = 1.f / (redsum[wn2][0][l31] + redsum[wn2][1][l31]);

    // ---- epilogue: n = nrow, d = (2wm2+i2)*32 + (r&3)+8g+4hi ----
    #pragma unroll
    for (int i2 = 0; i2 < 2; ++i2) {
        float* ob = out + (size_t)(b * Ndim + nbase + nrow) * Ddim
                        + (2 * wm2 + i2) * 32;
        #pragma unroll
        for (int g = 0; g < 4; ++g) {
            float4 o;
            o.x = c[i2][4 * g + 0] * inv;
            o.y = c[i2][4 * g + 1] * inv;
            o.z = c[i2][4 * g + 2] * inv;
            o.w = c[i2][4 * g + 3] * inv;
            *(float4*)(ob + g * 8 + hi * 4) = o;
        }
    }
}

extern "C" void kernel_launch(void* const* d_in, const int* in_sizes, int n_in,
                              void* d_out, int out_size, void* d_ws, size_t ws_size,
                              hipStream_t stream) {
    const float* x = (const float*)d_in[0];   // (B,N,D)
    const float* w = (const float*)d_in[1];   // (1,D,M)
    float* out = (float*)d_out;
    (void)in_sizes; (void)n_in; (void)out_size; (void)ws_size;

    _Float16* wt = (_Float16*)d_ws;           // 384 KB
    _Float16* wd = wt + Ddim * Mdim;          // 384 KB

    jamb_prep<<<dim3(48), dim3(256), 0, stream>>>(w, wt, wd);
    jamb_mfma_kernel<<<dim3((Bdim * Ndim) / NT), dim3(NTHREADS), 0, stream>>>(x, wt, wd, out);
}